// Round 1
// baseline (167.107 us; speedup 1.0000x reference)
//
#include <hip/hip_runtime.h>

#define RS 7
#define SR 2
#define PD 10
#define CH (PD * RS * RS)   // 490
#define SCALE (1.0f / 16.0f)

__global__ __launch_bounds__(256) void psroi_align_kernel(
    const float* __restrict__ feat, const float* __restrict__ rois,
    float* __restrict__ out, int total, int H, int W)
{
    int o = blockIdx.x * blockDim.x + threadIdx.x;
    if (o >= total) return;

    // out[n][c][ph][pw], pw fastest -> coalesced store
    int pw = o % RS;
    int t  = o / RS;
    int ph = t % RS;
    t /= RS;
    int c = t % PD;
    int n = t / PD;

    const float* r = rois + (size_t)n * 5;
    int   bidx = (int)r[0];
    float sw = r[1] * SCALE - 0.5f;
    float sh = r[2] * SCALE - 0.5f;
    float ew = r[3] * SCALE - 0.5f;
    float eh = r[4] * SCALE - 0.5f;
    float bin_w = (ew - sw) * (1.0f / RS);
    float bin_h = (eh - sh) * (1.0f / RS);

    int cin = (c * RS + ph) * RS + pw;
    const float* __restrict__ base = feat + (size_t)(bidx * CH + cin) * H * W;

    float acc = 0.0f;
    #pragma unroll
    for (int iy = 0; iy < SR; ++iy) {
        float y  = sh + ((float)ph + ((float)iy + 0.5f) * (1.0f / SR)) * bin_h;
        bool  vy = (y >= -1.0f) && (y <= (float)H);
        float yy = fmaxf(y, 0.0f);
        int   y0 = min((int)floorf(yy), H - 1);
        int   y1 = min(y0 + 1, H - 1);
        float yc = (y0 >= H - 1) ? (float)y0 : yy;
        float ly = yc - (float)y0;
        float hy = 1.0f - ly;
        #pragma unroll
        for (int ix = 0; ix < SR; ++ix) {
            float x  = sw + ((float)pw + ((float)ix + 0.5f) * (1.0f / SR)) * bin_w;
            bool  vx = (x >= -1.0f) && (x <= (float)W);
            float xx = fmaxf(x, 0.0f);
            int   x0 = min((int)floorf(xx), W - 1);
            int   x1 = min(x0 + 1, W - 1);
            float xc = (x0 >= W - 1) ? (float)x0 : xx;
            float lx = xc - (float)x0;
            float hx = 1.0f - lx;

            float v00 = base[y0 * W + x0];
            float v01 = base[y0 * W + x1];
            float v10 = base[y1 * W + x0];
            float v11 = base[y1 * W + x1];
            float v = hy * (hx * v00 + lx * v01) + ly * (hx * v10 + lx * v11);
            if (vy && vx) acc += v;
        }
    }
    out[o] = acc * (1.0f / (SR * SR));
}

extern "C" void kernel_launch(void* const* d_in, const int* in_sizes, int n_in,
                              void* d_out, int out_size, void* d_ws, size_t ws_size,
                              hipStream_t stream) {
    const float* feat = (const float*)d_in[0];
    const float* rois = (const float*)d_in[1];
    float* out = (float*)d_out;

    const int H = 100, W = 100;
    int N = in_sizes[1] / 5;
    int total = N * PD * RS * RS;   // == out_size

    int block = 256;
    int grid = (total + block - 1) / block;
    psroi_align_kernel<<<grid, block, 0, stream>>>(feat, rois, out, total, H, W);
}

// Round 2
// 42.359 us; speedup vs baseline: 3.9450x; 3.9450x over previous
//
#include <hip/hip_runtime.h>

#define RS 7
#define SR 2
#define PD 10
#define CH (PD * RS * RS)   // 490
#define SCALE (1.0f / 16.0f)
#define HH 100
#define WW 100
#define NB 4                // batch size

// ---- kernel 1: bucket ROI indices by batch (single block) ----
__global__ void build_lists_kernel(const float* __restrict__ rois, int N,
                                   int* __restrict__ counts, int* __restrict__ lists) {
    __shared__ int cnt[NB];
    int tid = threadIdx.x;
    if (tid < NB) cnt[tid] = 0;
    __syncthreads();
    for (int n = tid; n < N; n += blockDim.x) {
        int b = (int)rois[(size_t)n * 5];
        int pos = atomicAdd(&cnt[b], 1);
        lists[b * N + pos] = n;
    }
    __syncthreads();
    if (tid < NB) counts[tid] = cnt[tid];
}

// ---- kernel 2: one block per (batch, plane); plane staged in LDS ----
__global__ __launch_bounds__(256) void psroi_plane_kernel(
    const float* __restrict__ feat, const float* __restrict__ rois,
    const int* __restrict__ counts, const int* __restrict__ lists,
    float* __restrict__ out, int N)
{
    __shared__ float plane[HH * WW];   // 40 KB
    int bid = blockIdx.x;
    int b   = bid / CH;
    int cin = bid % CH;

    // coalesced float4 stage of the whole plane
    const float4* src = (const float4*)(feat + (size_t)(b * CH + cin) * (HH * WW));
    float4* dst = (float4*)plane;
    for (int i = threadIdx.x; i < (HH * WW) / 4; i += blockDim.x) dst[i] = src[i];
    __syncthreads();

    int pw = cin % RS;
    int ph = (cin / RS) % RS;

    int cnt = counts[b];
    const int* __restrict__ list = lists + b * N;

    for (int i = threadIdx.x; i < cnt; i += blockDim.x) {
        int n = list[i];
        const float* r = rois + (size_t)n * 5;
        float sw = r[1] * SCALE - 0.5f;
        float sh = r[2] * SCALE - 0.5f;
        float bin_w = (r[3] * SCALE - 0.5f - sw) * (1.0f / RS);
        float bin_h = (r[4] * SCALE - 0.5f - sh) * (1.0f / RS);

        float acc = 0.0f;
        #pragma unroll
        for (int iy = 0; iy < SR; ++iy) {
            float y  = sh + ((float)ph + ((float)iy + 0.5f) * (1.0f / SR)) * bin_h;
            bool  vy = (y >= -1.0f) && (y <= (float)HH);
            float yy = fmaxf(y, 0.0f);
            int   y0 = min((int)floorf(yy), HH - 1);
            int   y1 = min(y0 + 1, HH - 1);
            float yc = (y0 >= HH - 1) ? (float)y0 : yy;
            float ly = yc - (float)y0;
            float hy = 1.0f - ly;
            #pragma unroll
            for (int ix = 0; ix < SR; ++ix) {
                float x  = sw + ((float)pw + ((float)ix + 0.5f) * (1.0f / SR)) * bin_w;
                bool  vx = (x >= -1.0f) && (x <= (float)WW);
                float xx = fmaxf(x, 0.0f);
                int   x0 = min((int)floorf(xx), WW - 1);
                int   x1 = min(x0 + 1, WW - 1);
                float xc = (x0 >= WW - 1) ? (float)x0 : xx;
                float lx = xc - (float)x0;
                float hx = 1.0f - lx;

                float v00 = plane[y0 * WW + x0];
                float v01 = plane[y0 * WW + x1];
                float v10 = plane[y1 * WW + x0];
                float v11 = plane[y1 * WW + x1];
                float v = hy * (hx * v00 + lx * v01) + ly * (hx * v10 + lx * v11);
                if (vy && vx) acc += v;
            }
        }
        out[(size_t)n * CH + cin] = acc * (1.0f / (SR * SR));
    }
}

// ---- fallback (round-1 kernel) if ws too small ----
__global__ __launch_bounds__(256) void psroi_naive_kernel(
    const float* __restrict__ feat, const float* __restrict__ rois,
    float* __restrict__ out, int total)
{
    int o = blockIdx.x * blockDim.x + threadIdx.x;
    if (o >= total) return;
    int cin = o % CH;
    int n = o / CH;
    int pw = cin % RS;
    int ph = (cin / RS) % RS;
    const float* r = rois + (size_t)n * 5;
    int bidx = (int)r[0];
    float sw = r[1] * SCALE - 0.5f;
    float sh = r[2] * SCALE - 0.5f;
    float bin_w = (r[3] * SCALE - 0.5f - sw) * (1.0f / RS);
    float bin_h = (r[4] * SCALE - 0.5f - sh) * (1.0f / RS);
    const float* __restrict__ base = feat + (size_t)(bidx * CH + cin) * (HH * WW);
    float acc = 0.0f;
    #pragma unroll
    for (int iy = 0; iy < SR; ++iy) {
        float y  = sh + ((float)ph + ((float)iy + 0.5f) * (1.0f / SR)) * bin_h;
        bool  vy = (y >= -1.0f) && (y <= (float)HH);
        float yy = fmaxf(y, 0.0f);
        int   y0 = min((int)floorf(yy), HH - 1);
        int   y1 = min(y0 + 1, HH - 1);
        float yc = (y0 >= HH - 1) ? (float)y0 : yy;
        float ly = yc - (float)y0;
        float hy = 1.0f - ly;
        #pragma unroll
        for (int ix = 0; ix < SR; ++ix) {
            float x  = sw + ((float)pw + ((float)ix + 0.5f) * (1.0f / SR)) * bin_w;
            bool  vx = (x >= -1.0f) && (x <= (float)WW);
            float xx = fmaxf(x, 0.0f);
            int   x0 = min((int)floorf(xx), WW - 1);
            int   x1 = min(x0 + 1, WW - 1);
            float xc = (x0 >= WW - 1) ? (float)x0 : xx;
            float lx = xc - (float)x0;
            float hx = 1.0f - lx;
            float v00 = base[y0 * WW + x0];
            float v01 = base[y0 * WW + x1];
            float v10 = base[y1 * WW + x0];
            float v11 = base[y1 * WW + x1];
            float v = hy * (hx * v00 + lx * v01) + ly * (hx * v10 + lx * v11);
            if (vy && vx) acc += v;
        }
    }
    out[o] = acc * (1.0f / (SR * SR));
}

extern "C" void kernel_launch(void* const* d_in, const int* in_sizes, int n_in,
                              void* d_out, int out_size, void* d_ws, size_t ws_size,
                              hipStream_t stream) {
    const float* feat = (const float*)d_in[0];
    const float* rois = (const float*)d_in[1];
    float* out = (float*)d_out;
    int N = in_sizes[1] / 5;

    size_t need = 16 + (size_t)NB * N * sizeof(int);
    if (ws_size >= need) {
        int* counts = (int*)d_ws;                 // 4 ints (16 B slot)
        int* lists  = (int*)((char*)d_ws + 16);   // NB * N ints
        build_lists_kernel<<<1, 256, 0, stream>>>(rois, N, counts, lists);
        psroi_plane_kernel<<<NB * CH, 256, 0, stream>>>(feat, rois, counts, lists, out, N);
    } else {
        int total = N * CH;
        psroi_naive_kernel<<<(total + 255) / 256, 256, 0, stream>>>(feat, rois, out, total);
    }
}